// Round 11
// baseline (459.313 us; speedup 1.0000x reference)
//
#include <hip/hip_runtime.h>

// LSTMNextToken: embed-gather -> 2x LSTM -> LayerNorm -> tied-embedding head.
// I/O dtypes: float tensors are float32; x is int32. Internals f16/bf16 MFMA.
//
// R16 = R15 + RACE FIX: __syncthreads() between xL/hLh LDS staging and
// load_src(0). R14/R15 core-dumped because load_src read xL entries written
// by OTHER threads with no intervening barrier -> garbage token index ->
// wild EW address -> memory fault. R9 had the same latent race but ~100
// resident-weight global loads between write and read hid it by timing.
// R6/R12/R13 (all passing) had the barrier in the right place.
//
//  k_init : blocks 0..432 = EW precompute; blocks 433.. = embF bf16
//           frag-major + b1s + {Whh0,Wih1,Whh1} f16 frag-major (L2, 123KB ea).
//  k_rec  : grid 256, TB=16, 512 thr, CROSS-LAYER PIPELINED (17 super-steps
//           x 2 barriers vs R13's 33): step s = layer0(t=s) + layer1(t=s-1)
//           MFMA + head(t=s-2) in phase A; both gate-maths + shuffle-LN in
//           phase B. h0 handoff via hLh0 LDS (no hb0 global). ALL weights
//           streamed from frag-major L2 -- zero resident weight regs.
//           LDS: 2*30976 + 2*4352 + 8704 + 1024 = 80384 B.
// Evidence: R9 passed (structure numerically correct); R13 = 155us at 33
// phases (fixed ~4.7us/step barrier latency). Spill tripwire: FETCH >> 100MB.

#define VSZ 433
#define DIM 120
#define BSZ 4096
#define SEQ 16
#define H4  480
#define KP  128
#define NPAD 448
#define NT_HEAD 28
#define TB  16
#define GP  484          // gates LDS row pad (2-way banks = free)
#define HP  136          // h-state LDS row pad in f16/bf16

typedef unsigned int   u32;
typedef unsigned short u16;
typedef __attribute__((ext_vector_type(8))) short    v8bf;
typedef __attribute__((ext_vector_type(8))) _Float16 v8h;
typedef __attribute__((ext_vector_type(4))) float    v4f;

__device__ __forceinline__ u16 f2bf(float f){ // RNE
  union{float f;u32 u;}z; z.f=f;
  u32 u = z.u + 0x7fffu + ((z.u>>16)&1u);
  return (u16)(u>>16);
}
__device__ __forceinline__ u32 packh2(float a, float b){
  union{_Float16 h[2]; u32 u;} z;
  z.h[0] = (_Float16)a; z.h[1] = (_Float16)b;
  return z.u;
}

// ---------------- workspace layout (bytes, 256-aligned) ----------------
#define EW_OFF    0u          // 433*480*4   = 831360
#define B1S_OFF   831488u     // 480*4       = 1920
#define EMBF_OFF  833408u     // 448*128*2   = 114688
#define W0F_OFF   948096u     // 30*4*512*2  = 122880  (Whh0 frag-major f16)
#define W1F_OFF   1070976u    // 122880                (Wih1 frag-major f16)
#define WH1F_OFF  1193856u    // 122880                (Whh1 frag-major f16; end ~1.32 MB)

#define WELEM     61440       // 30*4*512 f16 elements per weight buffer
#define PREP_N    (NPAD*KP + H4 + 3*WELEM)   // 57344+480+184320 = 242144
#define PREP_BLKS ((PREP_N + 511)/512)       // 473

// ---------------- k_init: EW + embF/b1s + frag-major weights ----------------
__global__ __launch_bounds__(512) void k_init(const float* __restrict__ embed,
                                              const float* __restrict__ Wih0,
                                              const float* __restrict__ bih0,
                                              const float* __restrict__ bhh0,
                                              const float* __restrict__ Whh0,
                                              const float* __restrict__ Wih1,
                                              const float* __restrict__ Whh1,
                                              const float* __restrict__ bih1,
                                              const float* __restrict__ bhh1,
                                              float* __restrict__ EW,
                                              u16* __restrict__ embF,
                                              float* __restrict__ b1s,
                                              _Float16* __restrict__ w0F,
                                              _Float16* __restrict__ w1F,
                                              _Float16* __restrict__ wh1F)
{
  __shared__ float e[DIM];
  const int tid = threadIdx.x;
  if (blockIdx.x < VSZ) {
    const int v = blockIdx.x;
    if (tid < DIM) e[tid] = embed[v*DIM + tid];
    __syncthreads();
    if (tid < H4) {
      float acc = bih0[tid] + bhh0[tid];
      #pragma unroll
      for (int k0 = 0; k0 < DIM; k0 += 4) {
        float4 w = *(const float4*)(Wih0 + tid*DIM + k0);
        acc = fmaf(e[k0+0], w.x, acc);
        acc = fmaf(e[k0+1], w.y, acc);
        acc = fmaf(e[k0+2], w.z, acc);
        acc = fmaf(e[k0+3], w.w, acc);
      }
      EW[v*H4 + tid] = acc;
    }
  } else {
    const int idx = (blockIdx.x - VSZ)*512 + tid;
    if (idx < NPAD*KP) {
      // embF frag-major: ((nt*4+kt)*64 + lane)*8 + j = bf16(embed[nt*16+cl][kt*32+quad*8+j])
      int n = idx >> 7, k = idx & 127;
      int nt = n >> 4, cl = n & 15, kt = k >> 5, quad = (k >> 3) & 3, j = k & 7;
      int fidx = ((((nt*4 + kt)*4 + quad)*16 + cl) << 3) + j;
      embF[fidx] = (n < VSZ && k < DIM) ? f2bf(embed[n*DIM + k]) : (u16)0;
    } else if (idx < NPAD*KP + H4) {
      int g = idx - NPAD*KP;
      b1s[g] = bih1[g] + bhh1[g];
    } else if (idx < PREP_N) {
      int i0 = idx - (NPAD*KP + H4);
      int m  = (i0 >= 2*WELEM) ? 2 : (i0 >= WELEM) ? 1 : 0;
      int r0 = i0 - m*WELEM;
      int f = r0 >> 9, r = r0 & 511, lane = r >> 3, j = r & 7;
      int nt = f >> 2, kt = f & 3, cl = lane & 15, quad = lane >> 4;
      int k = kt*32 + quad*8 + j, n = nt*16 + cl;
      const float* src = (m == 0) ? Whh0 : (m == 1) ? Wih1 : Whh1;
      _Float16* dst = (m == 0) ? w0F : (m == 1) ? w1F : wh1F;
      dst[r0] = (k < DIM) ? (_Float16)src[n*DIM + k] : (_Float16)0.f;
    }
  }
}

// ---------------- k_rec: cross-layer pipelined 2-layer LSTM + LN + head ----------------
__global__ __launch_bounds__(512) void k_rec(const float* __restrict__ EW,
                                             const int* __restrict__ x,
                                             const float* __restrict__ b1s,
                                             const float* __restrict__ gamma,
                                             const float* __restrict__ beta,
                                             const _Float16* __restrict__ w0F,
                                             const _Float16* __restrict__ w1F,
                                             const _Float16* __restrict__ wh1F,
                                             const u16* __restrict__ embF,
                                             float* __restrict__ out)
{
  __shared__ float gLs0[TB][GP];                    // 30976 B  layer0 gates
  __shared__ float gLs1[TB][GP];                    // 30976 B  layer1 gates
  __shared__ __align__(16) _Float16 hLh0[TB][HP];   //  4352 B  h0 state (f16)
  __shared__ __align__(16) _Float16 hLh1[TB][HP];   //  4352 B  h1 state (f16)
  __shared__ __align__(16) u16 hnLD[2][TB][HP];     //  8704 B  LN'd h1 (bf16, dbuf)
  __shared__ int xL[TB*SEQ];                        //  1024 B
  // total 80384 B

  const int tid  = threadIdx.x;
  const int wave = tid >> 6, lane = tid & 63;
  const int cl   = lane & 15, quad = lane >> 4;
  const int b0   = blockIdx.x * TB;

  for (int i = tid; i < TB*SEQ; i += 512) xL[i] = x[b0*SEQ + i];
  for (int i = tid; i < TB*HP; i += 512) {
    (&hLh0[0][0])[i] = (_Float16)0.f;
    (&hLh1[0][0])[i] = (_Float16)0.f;
  }
  __syncthreads();   // RACE FIX: xL + hLh staging visible BEFORE load_src/phase A
                     // (R14/R15 crash root cause: cross-thread xL read w/o barrier)

  float bias[4];
  #pragma unroll
  for (int i = 0; i < 4; ++i) {
    const int nt = wave*4 + i;
    bias[i] = (nt < 30) ? b1s[nt*16 + cl] : 0.f;
  }

  float srcv[4][4] = {{0.f,0.f,0.f,0.f},{0.f,0.f,0.f,0.f},
                      {0.f,0.f,0.f,0.f},{0.f,0.f,0.f,0.f}};
  auto load_src = [&](int t) {
    #pragma unroll
    for (int i = 0; i < 4; ++i) {
      const int nt = wave*4 + i;
      if (nt < 30) {
        const int n = nt*16 + cl;
        #pragma unroll
        for (int r = 0; r < 4; ++r)
          srcv[i][r] = EW[(size_t)xL[(quad*4 + r)*SEQ + t]*H4 + n];
      }
    }
  };
  load_src(0);

  // phase-B mapping: wave owns rows {2w,2w+1}; lane l<60 owns dims {2l,2l+1}
  const int prow = wave*2;
  const bool act = lane < 60;
  const int d0   = lane*2;
  float gmm[2] = {0.f, 0.f}, bta[2] = {0.f, 0.f};
  if (act) {
    gmm[0] = gamma[d0]; gmm[1] = gamma[d0+1];
    bta[0] = beta[d0];  bta[1] = beta[d0+1];
  }
  float C0[2][2] = {{0.f,0.f},{0.f,0.f}};
  float C1[2][2] = {{0.f,0.f},{0.f,0.f}};

  for (int s = 0; s <= SEQ; ++s) {
    // ================= phase A: MFMA (all weights streamed from L2) ========
    // layer0 gates0(t=s):   A=hLh0 (h0[s-1]), B=w0F
    // layer1 gates1(t=s-1): A0=hLh0 (shared read), B=w1F; A1=hLh1 (h1[s-2]), B=wh1F
    v4f acc0[4], acc1[4];
    #pragma unroll
    for (int i = 0; i < 4; ++i) {
      acc0[i][0]=srcv[i][0]; acc0[i][1]=srcv[i][1];
      acc0[i][2]=srcv[i][2]; acc0[i][3]=srcv[i][3];
      acc1[i] = (v4f){bias[i], bias[i], bias[i], bias[i]};
    }
    #pragma unroll
    for (int kt = 0; kt < 4; ++kt) {
      v8h hbF = *(const v8h*)&hLh0[cl][kt*32 + quad*8];
      v8h h1F = *(const v8h*)&hLh1[cl][kt*32 + quad*8];
      #pragma unroll
      for (int i = 0; i < 4; ++i) {
        const int nt = wave*4 + i;
        if (nt < 30) {
          const size_t fb = (((size_t)nt*4 + kt)*64 + lane)*8;
          if (s < SEQ) {
            v8h w0 = *(const v8h*)&w0F[fb];
            acc0[i] = __builtin_amdgcn_mfma_f32_16x16x32_f16(hbF, w0, acc0[i], 0, 0, 0);
          }
          if (s >= 1) {
            v8h w1 = *(const v8h*)&w1F[fb];
            acc1[i] = __builtin_amdgcn_mfma_f32_16x16x32_f16(hbF, w1, acc1[i], 0, 0, 0);
            v8h wh1 = *(const v8h*)&wh1F[fb];
            acc1[i] = __builtin_amdgcn_mfma_f32_16x16x32_f16(h1F, wh1, acc1[i], 0, 0, 0);
          }
        }
      }
    }
    // head for t=s-2 (hnLD parity (s-2)&1 == s&1), overlaps the LSTM chain
    if (s >= 2) {
      const int t = s - 2;
      v8bf a[4];
      #pragma unroll
      for (int kt = 0; kt < 4; ++kt)
        a[kt] = *(const v8bf*)&hnLD[s & 1][cl][kt*32 + quad*8];
      #pragma unroll
      for (int j = 0; j < 4; ++j) {
        const int nth = wave + 8*j;         // waves 0-3: 4 tiles, 4-7: 3 tiles
        if (nth < NT_HEAD) {
          v8bf bfr[4];
          #pragma unroll
          for (int kt = 0; kt < 4; ++kt)
            bfr[kt] = *(const v8bf*)&embF[(((size_t)nth*4 + kt)*64 + lane)*8];
          v4f hacc = {0.f, 0.f, 0.f, 0.f};
          #pragma unroll
          for (int kt = 0; kt < 4; ++kt)
            hacc = __builtin_amdgcn_mfma_f32_16x16x32_bf16(a[kt], bfr[kt], hacc, 0, 0, 0);
          const int n = nth*16 + cl;
          if (n < VSZ) {
            #pragma unroll
            for (int r = 0; r < 4; ++r)
              out[((size_t)(b0 + quad*4 + r)*SEQ + t)*VSZ + n] = hacc[r];
          }
        }
      }
    }
    if (s + 1 < SEQ) load_src(s + 1);
    #pragma unroll
    for (int i = 0; i < 4; ++i) {
      const int nt = wave*4 + i;
      if (nt < 30) {
        #pragma unroll
        for (int r = 0; r < 4; ++r) {
          if (s < SEQ) gLs0[quad*4 + r][nt*16 + cl] = acc0[i][r];
          if (s >= 1) gLs1[quad*4 + r][nt*16 + cl] = acc1[i][r];
        }
      }
    }
    __syncthreads();   // sync1: gates visible

    // ================= phase B: gate math =================
    if (s < SEQ) {   // layer0: h0[s]
      #pragma unroll
      for (int rr = 0; rr < 2; ++rr) {
        const int row = prow + rr;
        if (act) {
          const float2 gi = *(const float2*)&gLs0[row][d0      ];
          const float2 gf = *(const float2*)&gLs0[row][d0 + 120];
          const float2 gg = *(const float2*)&gLs0[row][d0 + 240];
          const float2 go = *(const float2*)&gLs0[row][d0 + 360];
          float h2[2];
          #pragma unroll
          for (int k = 0; k < 2; ++k) {
            const float vi = k ? gi.y : gi.x, vf = k ? gf.y : gf.x;
            const float vg = k ? gg.y : gg.x, vo = k ? go.y : go.x;
            const float si = 1.f / (1.f + __expf(-vi));
            const float sf = 1.f / (1.f + __expf(-vf));
            const float tg = 1.f - 2.f / (__expf(2.f*vg) + 1.f);
            const float so = 1.f / (1.f + __expf(-vo));
            const float c  = sf * C0[rr][k] + si * tg;
            C0[rr][k] = c;
            const float tc = 1.f - 2.f / (__expf(2.f*c) + 1.f);
            h2[k] = so * tc;
          }
          *(u32*)&hLh0[row][d0] = packh2(h2[0], h2[1]);
        }
      }
    }
    if (s >= 1) {    // layer1: h1[s-1] + LN -> hnLD[(s-1)&1]
      float h2[2][2] = {{0.f,0.f},{0.f,0.f}};
      float s1[2] = {0.f, 0.f}, s2[2] = {0.f, 0.f};
      #pragma unroll
      for (int rr = 0; rr < 2; ++rr) {
        const int row = prow + rr;
        if (act) {
          const float2 gi = *(const float2*)&gLs1[row][d0      ];
          const float2 gf = *(const float2*)&gLs1[row][d0 + 120];
          const float2 gg = *(const float2*)&gLs1[row][d0 + 240];
          const float2 go = *(const float2*)&gLs1[row][d0 + 360];
          #pragma unroll
          for (int k = 0; k < 2; ++k) {
            const float vi = k ? gi.y : gi.x, vf = k ? gf.y : gf.x;
            const float vg = k ? gg.y : gg.x, vo = k ? go.y : go.x;
            const float si = 1.f / (1.f + __expf(-vi));
            const float sf = 1.f / (1.f + __expf(-vf));
            const float tg = 1.f - 2.f / (__expf(2.f*vg) + 1.f);
            const float so = 1.f / (1.f + __expf(-vo));
            const float c  = sf * C1[rr][k] + si * tg;
            C1[rr][k] = c;
            const float tc = 1.f - 2.f / (__expf(2.f*c) + 1.f);
            const float h  = so * tc;
            h2[rr][k] = h;
            s1[rr] += h;
            s2[rr] = fmaf(h, h, s2[rr]);
          }
          *(u32*)&hLh1[row][d0] = packh2(h2[rr][0], h2[rr][1]);
        }
      }
      #pragma unroll
      for (int m = 32; m >= 1; m >>= 1) {
        s1[0] += __shfl_xor(s1[0], m);
        s2[0] += __shfl_xor(s2[0], m);
        s1[1] += __shfl_xor(s1[1], m);
        s2[1] += __shfl_xor(s2[1], m);
      }
      #pragma unroll
      for (int rr = 0; rr < 2; ++rr) {
        const int row = prow + rr;
        const float mu = s1[rr] * (1.f/DIM);
        const float var = s2[rr] * (1.f/DIM) - mu*mu;
        const float rs = rsqrtf(var + 1e-5f);
        if (act) {
          const float v0 = fmaf((h2[rr][0] - mu)*rs, gmm[0], bta[0]);
          const float v1 = fmaf((h2[rr][1] - mu)*rs, gmm[1], bta[1]);
          *(u32*)&hnLD[(s-1) & 1][row][d0] = (u32)f2bf(v0) | ((u32)f2bf(v1) << 16);
        } else {
          *(u32*)&hnLD[(s-1) & 1][row][120 + 2*(lane - 60)] = 0u;
        }
      }
    }
    __syncthreads();   // sync2: hLh0/hLh1/hnLD stable
  }

  // tail: head for t=SEQ-1 (parity 1)
  {
    const int t = SEQ - 1;
    v8bf a[4];
    #pragma unroll
    for (int kt = 0; kt < 4; ++kt)
      a[kt] = *(const v8bf*)&hnLD[1][cl][kt*32 + quad*8];
    #pragma unroll
    for (int j = 0; j < 4; ++j) {
      const int nth = wave + 8*j;
      if (nth < NT_HEAD) {
        v8bf bfr[4];
        #pragma unroll
        for (int kt = 0; kt < 4; ++kt)
          bfr[kt] = *(const v8bf*)&embF[(((size_t)nth*4 + kt)*64 + lane)*8];
        v4f hacc = {0.f, 0.f, 0.f, 0.f};
        #pragma unroll
        for (int kt = 0; kt < 4; ++kt)
          hacc = __builtin_amdgcn_mfma_f32_16x16x32_bf16(a[kt], bfr[kt], hacc, 0, 0, 0);
        const int n = nth*16 + cl;
        if (n < VSZ) {
          #pragma unroll
          for (int r = 0; r < 4; ++r)
            out[((size_t)(b0 + quad*4 + r)*SEQ + t)*VSZ + n] = hacc[r];
        }
      }
    }
  }
}

// ---------------- launch ----------------
extern "C" void kernel_launch(void* const* d_in, const int* in_sizes, int n_in,
                              void* d_out, int out_size, void* d_ws, size_t ws_size,
                              hipStream_t stream)
{
  (void)in_sizes; (void)n_in; (void)out_size; (void)ws_size;
  const int*   x     = (const int*)d_in[0];
  const float* embed = (const float*)d_in[1];
  const float* Wih0  = (const float*)d_in[2];
  const float* Whh0  = (const float*)d_in[3];
  const float* bih0  = (const float*)d_in[4];
  const float* bhh0  = (const float*)d_in[5];
  const float* Wih1  = (const float*)d_in[6];
  const float* Whh1  = (const float*)d_in[7];
  const float* bih1  = (const float*)d_in[8];
  const float* bhh1  = (const float*)d_in[9];
  const float* gamma = (const float*)d_in[10];
  const float* beta  = (const float*)d_in[11];

  char* ws = (char*)d_ws;
  float*     EW   = (float*)(ws + EW_OFF);
  float*     b1s  = (float*)(ws + B1S_OFF);
  u16*       embF = (u16*)(ws + EMBF_OFF);
  _Float16*  w0F  = (_Float16*)(ws + W0F_OFF);
  _Float16*  w1F  = (_Float16*)(ws + W1F_OFF);
  _Float16*  wh1F = (_Float16*)(ws + WH1F_OFF);

  k_init<<<VSZ + PREP_BLKS, 512, 0, stream>>>(embed, Wih0, bih0, bhh0,
                                              Whh0, Wih1, Whh1, bih1, bhh1,
                                              EW, embF, b1s, w0F, w1F, wh1F);
  k_rec <<<BSZ/TB, 512, 0, stream>>>(EW, x, b1s, gamma, beta,
                                     w0F, w1F, wh1F, embF, (float*)d_out);
}

// Round 12
// 320.251 us; speedup vs baseline: 1.4342x; 1.4342x over previous
//
#include <hip/hip_runtime.h>

// LSTMNextToken: embed-gather -> 2x LSTM -> LayerNorm -> tied-embedding head.
// I/O dtypes: float tensors are float32; x is int32. Internals f16/bf16 MFMA.
//
// R17 = R13 (fused 2-phase, resident weights, TB=16, grid 256) with the
// phase-B cross-wave handoff ELIMINATED via gate-interleaved weight rows:
//   permuted row p = d*4 + g  (orig row g*120+d), applied at fragment-load
//   time (orow = (p&3)*120 + (p>>2)) to Whh0/Wih1/Whh1/EW/b1s.
// Wave w then owns ALL 4 gates for dims [16w,16w+16) x all 16 rows in its
// own accumulators -> gate math after a SAME-WAVE LDS scratch transpose
// (wave_barrier + lgkmcnt, no block barrier). h-state double-buffered ->
// 1 barrier/step (R13: 2). Layer-1 LN: per-wave partials -> LDS; apply
// deferred 1 step (h kept in regs); head deferred 2 steps (hnLD parity).
// hb0 kept in LDS (no global round-trip). Barriers 67 -> 35.
// LDS: 34816(scr)+8704*3(hLh0,hLh1,hnLD)+69632(hb0L)+4096(prt)+1024(xL)
//    = 135680 B. Math per element identical to R13 (LN partial-sum order
//    differs, sub-bf16-quantum). Spill tripwire: FETCH >> 100 MB.

#define VSZ 433
#define DIM 120
#define BSZ 4096
#define SEQ 16
#define H4  480
#define KP  128
#define NPAD 448
#define NT_HEAD 28
#define TB  16
#define HP  136          // h-state LDS row pad in f16/bf16 (272 B = 17*16)
#define SCRW 68          // scratch row pad (f32)

typedef unsigned int   u32;
typedef unsigned short u16;
typedef __attribute__((ext_vector_type(8))) short    v8bf;
typedef __attribute__((ext_vector_type(8))) _Float16 v8h;
typedef __attribute__((ext_vector_type(4))) float    v4f;

__device__ __forceinline__ u16 f2bf(float f){ // RNE
  union{float f;u32 u;}z; z.f=f;
  u32 u = z.u + 0x7fffu + ((z.u>>16)&1u);
  return (u16)(u>>16);
}
__device__ __forceinline__ u32 packh2(float a, float b){
  union{_Float16 h[2]; u32 u;} z;
  z.h[0] = (_Float16)a; z.h[1] = (_Float16)b;
  return z.u;
}

// ---------------- workspace layout (bytes, 256-aligned) ----------------
#define EW_OFF    0u          // 433*480*4   = 831360
#define B1S_OFF   831488u     // 480*4       = 1920
#define EMBF_OFF  833408u     // 448*128*2   = 114688 (frag-major bf16)

#define PREP_N    (NPAD*KP + H4)             // 57824
#define PREP_BLKS ((PREP_N + 511)/512)       // 113

// ---------------- k_init: EW precompute + embF frag-major + b1s ----------------
__global__ __launch_bounds__(512) void k_init(const float* __restrict__ embed,
                                              const float* __restrict__ Wih0,
                                              const float* __restrict__ bih0,
                                              const float* __restrict__ bhh0,
                                              const float* __restrict__ bih1,
                                              const float* __restrict__ bhh1,
                                              float* __restrict__ EW,
                                              u16* __restrict__ embF,
                                              float* __restrict__ b1s)
{
  __shared__ float e[DIM];
  const int tid = threadIdx.x;
  if (blockIdx.x < VSZ) {
    const int v = blockIdx.x;
    if (tid < DIM) e[tid] = embed[v*DIM + tid];
    __syncthreads();
    if (tid < H4) {
      float acc = bih0[tid] + bhh0[tid];
      #pragma unroll
      for (int k0 = 0; k0 < DIM; k0 += 4) {
        float4 w = *(const float4*)(Wih0 + tid*DIM + k0);
        acc = fmaf(e[k0+0], w.x, acc);
        acc = fmaf(e[k0+1], w.y, acc);
        acc = fmaf(e[k0+2], w.z, acc);
        acc = fmaf(e[k0+3], w.w, acc);
      }
      EW[v*H4 + tid] = acc;
    }
  } else {
    const int idx = (blockIdx.x - VSZ)*512 + tid;
    if (idx < NPAD*KP) {
      // embF frag-major: ((nt*4+kt)*64 + lane)*8 + j = bf16(embed[nt*16+cl][kt*32+quad*8+j])
      int n = idx >> 7, k = idx & 127;
      int nt = n >> 4, cl = n & 15, kt = k >> 5, quad = (k >> 3) & 3, j = k & 7;
      int fidx = ((((nt*4 + kt)*4 + quad)*16 + cl) << 3) + j;
      embF[fidx] = (n < VSZ && k < DIM) ? f2bf(embed[n*DIM + k]) : (u16)0;
    } else if (idx < PREP_N) {
      int g = idx - NPAD*KP;
      b1s[g] = bih1[g] + bhh1[g];
    }
  }
}

// ---------------- k_rec ----------------
__global__ __launch_bounds__(512) void k_rec(const float* __restrict__ Whh0,
                                             const float* __restrict__ EW,
                                             const int* __restrict__ x,
                                             const float* __restrict__ Wih1,
                                             const float* __restrict__ Whh1,
                                             const float* __restrict__ b1s,
                                             const float* __restrict__ gamma,
                                             const float* __restrict__ beta,
                                             const u16* __restrict__ embF,
                                             float* __restrict__ out)
{
  __shared__ float scr[8][TB][SCRW];                 // 34816 B per-wave gate scratch
  __shared__ __align__(16) _Float16 hLh0[2][TB][HP]; //  8704 B h0 dbuf (f16)
  __shared__ __align__(16) _Float16 hLh1[2][TB][HP]; //  8704 B h1 dbuf (f16)
  __shared__ __align__(16) u16 hnLD[2][TB][HP];      //  8704 B LN'd h1 dbuf (bf16)
  __shared__ __align__(16) _Float16 hb0L[SEQ][TB][HP];// 69632 B h0 all steps (f16)
  __shared__ float prt[2][TB][8][2];                 //  4096 B LN partials dbuf
  __shared__ int xL[TB*SEQ];                         //  1024 B
  // total 135680 B

  const int tid  = threadIdx.x;
  const int wave = tid >> 6, lane = tid & 63;
  const int cl   = lane & 15, quad = lane >> 4;
  const int b0   = blockIdx.x * TB;
  // phase-B mapping: lane owns row=lane&15, dims dl0..dl0+3
  const int row  = lane & 15, lg = lane >> 4;
  const int dl0  = wave*16 + lg*4;
  const bool vdim = (dl0 < DIM);

  for (int i = tid; i < TB*SEQ; i += 512) xL[i] = x[b0*SEQ + i];
  for (int i = tid; i < 2*TB*HP; i += 512) {
    (&hLh0[0][0][0])[i] = (_Float16)0.f;
    (&hLh1[0][0][0])[i] = (_Float16)0.f;
  }

  // permuted-row map: fragment row p = nt*16+cl -> original row (p&3)*120 + (p>>2)
  int orow[4];
  #pragma unroll
  for (int i = 0; i < 4; ++i) {
    const int p = (wave*4 + i)*16 + cl;
    orow[i] = (p & 3)*120 + (p >> 2);
  }

  // resident Whh0 fragments (permuted rows)
  v8h Bf0[4][4];
  #pragma unroll
  for (int i = 0; i < 4; ++i) {
    const bool vld = (wave*4 + i < 30);
    #pragma unroll
    for (int kt = 0; kt < 4; ++kt) {
      const int k0 = kt*32 + quad*8;
      v8h f = {0,0,0,0,0,0,0,0};
      if (vld && k0 < DIM) {
        float4 q0 = *(const float4*)(Whh0 + orow[i]*DIM + k0);
        float4 q1 = *(const float4*)(Whh0 + orow[i]*DIM + k0 + 4);
        f[0]=(_Float16)q0.x; f[1]=(_Float16)q0.y; f[2]=(_Float16)q0.z; f[3]=(_Float16)q0.w;
        f[4]=(_Float16)q1.x; f[5]=(_Float16)q1.y; f[6]=(_Float16)q1.z; f[7]=(_Float16)q1.w;
      }
      Bf0[i][kt] = f;
    }
  }

  float srcv[4][4] = {{0.f,0.f,0.f,0.f},{0.f,0.f,0.f,0.f},
                      {0.f,0.f,0.f,0.f},{0.f,0.f,0.f,0.f}};
  auto load_src = [&](int t) {
    #pragma unroll
    for (int i = 0; i < 4; ++i) {
      if (wave*4 + i < 30) {
        #pragma unroll
        for (int r = 0; r < 4; ++r)
          srcv[i][r] = EW[(size_t)xL[(quad*4 + r)*SEQ + t]*H4 + orow[i]];
      }
    }
  };
  __syncthreads();   // staging visible (incl. xL) BEFORE load_src — R16 race fix
  load_src(0);

  float C0[4] = {0.f, 0.f, 0.f, 0.f};

  // ================= PHASE 1: layer 0, 1 barrier/step =================
  for (int t = 0; t < SEQ; ++t) {
    v8h Af[4];
    #pragma unroll
    for (int kt = 0; kt < 4; ++kt)
      Af[kt] = *(const v8h*)&hLh0[t & 1][cl][kt*32 + quad*8];
    v4f acc[4];
    #pragma unroll
    for (int i = 0; i < 4; ++i) {
      acc[i][0]=srcv[i][0]; acc[i][1]=srcv[i][1];
      acc[i][2]=srcv[i][2]; acc[i][3]=srcv[i][3];
    }
    #pragma unroll
    for (int kt = 0; kt < 4; ++kt)
      #pragma unroll
      for (int i = 0; i < 4; ++i)
        if (wave*4 + i < 30)
          acc[i] = __builtin_amdgcn_mfma_f32_16x16x32_f16(Af[kt], Bf0[i][kt], acc[i], 0, 0, 0);
    if (t + 1 < SEQ) load_src(t + 1);
    #pragma unroll
    for (int i = 0; i < 4; ++i)
      if (wave*4 + i < 30) {
        #pragma unroll
        for (int r = 0; r < 4; ++r)
          scr[wave][quad*4 + r][16*i + cl] = acc[i][r];
      }
    // same-wave transpose: DS ops of one wave complete in order; fence compiler
    __builtin_amdgcn_wave_barrier();
    asm volatile("s_waitcnt lgkmcnt(0)" ::: "memory");
    __builtin_amdgcn_sched_barrier(0);
    float h0v[4];
    #pragma unroll
    for (int j = 0; j < 4; ++j) {
      const float4 gq = *(const float4*)&scr[wave][row][16*lg + 4*j];
      const float si = 1.f / (1.f + __expf(-gq.x));
      const float sf = 1.f / (1.f + __expf(-gq.y));
      const float tg = 1.f - 2.f / (__expf(2.f*gq.z) + 1.f);
      const float so = 1.f / (1.f + __expf(-gq.w));
      const float c  = sf * C0[j] + si * tg;
      C0[j] = c;
      const float tc = 1.f - 2.f / (__expf(2.f*c) + 1.f);
      h0v[j] = so * tc;
    }
    uint2 pk; pk.x = 0u; pk.y = 0u;
    if (vdim) { pk.x = packh2(h0v[0], h0v[1]); pk.y = packh2(h0v[2], h0v[3]); }
    *(uint2*)&hLh0[(t+1) & 1][row][dl0] = pk;
    *(uint2*)&hb0L[t][row][dl0] = pk;
    __syncthreads();   // the ONE barrier: h0(t) visible block-wide
  }

  // anti-hoist guard: keep phase-2 weight loads below phase 1 (R9 spill trap)
  const float* Wih1p = Wih1;
  const float* Whh1p = Whh1;
  const float* b1sp  = b1s;
  const float* gmp   = gamma;
  const float* btp   = beta;
  asm volatile("" : "+s"(Wih1p), "+s"(Whh1p), "+s"(b1sp), "+s"(gmp), "+s"(btp) :: "memory");

  // ================= PHASE 2 setup =================
  v8h Bi[4][4], Bh[4][4];
  float bias[4];
  #pragma unroll
  for (int i = 0; i < 4; ++i) {
    const bool vld = (wave*4 + i < 30);
    bias[i] = vld ? b1sp[orow[i]] : 0.f;
    #pragma unroll
    for (int kt = 0; kt < 4; ++kt) {
      const int k0 = kt*32 + quad*8;
      v8h fi = {0,0,0,0,0,0,0,0}, fh = {0,0,0,0,0,0,0,0};
      if (vld && k0 < DIM) {
        float4 q0 = *(const float4*)(Wih1p + orow[i]*DIM + k0);
        float4 q1 = *(const float4*)(Wih1p + orow[i]*DIM + k0 + 4);
        fi[0]=(_Float16)q0.x; fi[1]=(_Float16)q0.y; fi[2]=(_Float16)q0.z; fi[3]=(_Float16)q0.w;
        fi[4]=(_Float16)q1.x; fi[5]=(_Float16)q1.y; fi[6]=(_Float16)q1.z; fi[7]=(_Float16)q1.w;
        float4 p0 = *(const float4*)(Whh1p + orow[i]*DIM + k0);
        float4 p1 = *(const float4*)(Whh1p + orow[i]*DIM + k0 + 4);
        fh[0]=(_Float16)p0.x; fh[1]=(_Float16)p0.y; fh[2]=(_Float16)p0.z; fh[3]=(_Float16)p0.w;
        fh[4]=(_Float16)p1.x; fh[5]=(_Float16)p1.y; fh[6]=(_Float16)p1.z; fh[7]=(_Float16)p1.w;
      }
      Bi[i][kt] = fi;
      Bh[i][kt] = fh;
    }
  }
  float gmm4[4] = {0.f,0.f,0.f,0.f}, bta4[4] = {0.f,0.f,0.f,0.f};
  if (vdim) {
    #pragma unroll
    for (int j = 0; j < 4; ++j) { gmm4[j] = gmp[dl0+j]; bta4[j] = btp[dl0+j]; }
  }
  float C1[4] = {0.f,0.f,0.f,0.f};
  float h1prev[4] = {0.f,0.f,0.f,0.f};

  // ================= PHASE 2: layer1 + deferred LN + deferred head =================
  // iter s: applyLN(t=s-1) -> hnLD[(s-1)&1]; head(t=s-2) from hnLD[(s-2)&1];
  //         layer1 MFMA+gates(t=s) -> h1prev, hLh1[(s+1)&1], prt[s&1]. 1 barrier.
  for (int s = 0; s <= SEQ + 1; ++s) {
    // ---- (a) apply LN for t=s-1 (partials visible since last barrier)
    if (s >= 1 && s <= SEQ) {
      const float* pr = &prt[(s-1) & 1][row][0][0];
      const float4 q0 = *(const float4*)(pr);
      const float4 q1 = *(const float4*)(pr + 4);
      const float4 q2 = *(const float4*)(pr + 8);
      const float4 q3 = *(const float4*)(pr + 12);
      const float s1 = q0.x+q0.z + q1.x+q1.z + q2.x+q2.z + q3.x+q3.z;
      const float s2 = q0.y+q0.w + q1.y+q1.w + q2.y+q2.w + q3.y+q3.w;
      const float mu = s1 * (1.f/DIM);
      const float var = s2 * (1.f/DIM) - mu*mu;
      const float rs = rsqrtf(var + 1e-5f);
      uint2 pk; pk.x = 0u; pk.y = 0u;
      if (vdim) {
        const float v0 = fmaf((h1prev[0]-mu)*rs, gmm4[0], bta4[0]);
        const float v1 = fmaf((h1prev[1]-mu)*rs, gmm4[1], bta4[1]);
        const float v2 = fmaf((h1prev[2]-mu)*rs, gmm4[2], bta4[2]);
        const float v3 = fmaf((h1prev[3]-mu)*rs, gmm4[3], bta4[3]);
        pk.x = (u32)f2bf(v0) | ((u32)f2bf(v1) << 16);
        pk.y = (u32)f2bf(v2) | ((u32)f2bf(v3) << 16);
      }
      *(uint2*)&hnLD[(s-1) & 1][row][dl0] = pk;
    }
    // ---- (b) head for t=s-2 (hnLD written at iter s-1, barrier-separated)
    if (s >= 2) {
      const int t = s - 2;
      v8bf a[4];
      #pragma unroll
      for (int kt = 0; kt < 4; ++kt)
        a[kt] = *(const v8bf*)&hnLD[(s-2) & 1][cl][kt*32 + quad*8];
      #pragma unroll
      for (int j = 0; j < 4; ++j) {
        const int nth = wave + 8*j;
        if (nth < NT_HEAD) {
          v8bf bfr[4];
          #pragma unroll
          for (int kt = 0; kt < 4; ++kt)
            bfr[kt] = *(const v8bf*)&embF[(((size_t)nth*4 + kt)*64 + lane)*8];
          v4f hacc = {0.f, 0.f, 0.f, 0.f};
          #pragma unroll
          for (int kt = 0; kt < 4; ++kt)
            hacc = __builtin_amdgcn_mfma_f32_16x16x32_bf16(a[kt], bfr[kt], hacc, 0, 0, 0);
          const int n = nth*16 + cl;
          if (n < VSZ) {
            #pragma unroll
            for (int r = 0; r < 4; ++r)
              out[((size_t)(b0 + quad*4 + r)*SEQ + t)*VSZ + n] = hacc[r];
          }
        }
      }
    }
    // ---- (c) layer1 gates for t=s
    if (s < SEQ) {
      v8h A0[4], A1[4];
      #pragma unroll
      for (int kt = 0; kt < 4; ++kt) {
        A0[kt] = *(const v8h*)&hb0L[s][cl][kt*32 + quad*8];
        A1[kt] = *(const v8h*)&hLh1[s & 1][cl][kt*32 + quad*8];
      }
      v4f acc[4];
      #pragma unroll
      for (int i = 0; i < 4; ++i)
        acc[i] = (v4f){bias[i], bias[i], bias[i], bias[i]};
      #pragma unroll
      for (int kt = 0; kt < 4; ++kt)
        #pragma unroll
        for (int i = 0; i < 4; ++i)
          if (wave*4 + i < 30) {
            acc[i] = __builtin_amdgcn_mfma_f32_16x16x32_f16(A0[kt], Bi[i][kt], acc[i], 0, 0, 0);
            acc[i] = __builtin_amdgcn_mfma_f32_16x16x32_f16(A1[kt], Bh[i][kt], acc[i], 0, 0, 0);
          }
      #pragma unroll
      for (int i = 0; i < 4; ++i)
        if (wave*4 + i < 30) {
          #pragma unroll
          for (int r = 0; r < 4; ++r)
            scr[wave][quad*4 + r][16*i + cl] = acc[i][r];
        }
      __builtin_amdgcn_wave_barrier();
      asm volatile("s_waitcnt lgkmcnt(0)" ::: "memory");
      __builtin_amdgcn_sched_barrier(0);
      #pragma unroll
      for (int j = 0; j < 4; ++j) {
        const float4 gq = *(const float4*)&scr[wave][row][16*lg + 4*j];
        const float si = 1.f / (1.f + __expf(-gq.x));
        const float sf = 1.f / (1.f + __expf(-gq.y));
        const float tg = 1.f - 2.f / (__expf(2.f*gq.z) + 1.f);
        const float so = 1.f / (1.f + __expf(-gq.w));
        const float c  = sf * C1[j] + si * tg;
        C1[j] = c;
        const float tc = 1.f - 2.f / (__expf(2.f*c) + 1.f);
        h1prev[j] = so * tc;
      }
      uint2 pk; pk.x = 0u; pk.y = 0u;
      if (vdim) { pk.x = packh2(h1prev[0], h1prev[1]); pk.y = packh2(h1prev[2], h1prev[3]); }
      *(uint2*)&hLh1[(s+1) & 1][row][dl0] = pk;
      // LN partials for t=s (4-lane cross-reduce over lane-groups sharing row)
      float s1l = 0.f, s2l = 0.f;
      if (vdim) {
        s1l = h1prev[0] + h1prev[1] + h1prev[2] + h1prev[3];
        s2l = h1prev[0]*h1prev[0] + h1prev[1]*h1prev[1]
            + h1prev[2]*h1prev[2] + h1prev[3]*h1prev[3];
      }
      s1l += __shfl_xor(s1l, 16); s1l += __shfl_xor(s1l, 32);
      s2l += __shfl_xor(s2l, 16); s2l += __shfl_xor(s2l, 32);
      if (lane < 16) {
        prt[s & 1][lane][wave][0] = s1l;
        prt[s & 1][lane][wave][1] = s2l;
      }
    }
    __syncthreads();   // the ONE barrier per iteration
  }
}

// ---------------- launch ----------------
extern "C" void kernel_launch(void* const* d_in, const int* in_sizes, int n_in,
                              void* d_out, int out_size, void* d_ws, size_t ws_size,
                              hipStream_t stream)
{
  (void)in_sizes; (void)n_in; (void)out_size; (void)ws_size;
  const int*   x     = (const int*)d_in[0];
  const float* embed = (const float*)d_in[1];
  const float* Wih0  = (const float*)d_in[2];
  const float* Whh0  = (const float*)d_in[3];
  const float* bih0  = (const float*)d_in[4];
  const float* bhh0  = (const float*)d_in[5];
  const float* Wih1  = (const float*)d_in[6];
  const float* Whh1  = (const float*)d_in[7];
  const float* bih1  = (const float*)d_in[8];
  const float* bhh1  = (const float*)d_in[9];
  const float* gamma = (const float*)d_in[10];
  const float* beta  = (const float*)d_in[11];

  char* ws = (char*)d_ws;
  float* EW   = (float*)(ws + EW_OFF);
  float* b1s  = (float*)(ws + B1S_OFF);
  u16*   embF = (u16*)(ws + EMBF_OFF);

  k_init<<<VSZ + PREP_BLKS, 512, 0, stream>>>(embed, Wih0, bih0, bhh0, bih1, bhh1,
                                              EW, embF, b1s);
  k_rec <<<BSZ/TB, 512, 0, stream>>>(Whh0, EW, x, Wih1, Whh1, b1s, gamma, beta,
                                     embF, (float*)d_out);
}

// Round 13
// 263.699 us; speedup vs baseline: 1.7418x; 1.2145x over previous
//
#include <hip/hip_runtime.h>

// LSTMNextToken: embed-gather -> 2x LSTM -> LayerNorm -> tied-embedding head.
// I/O dtypes: float tensors are float32; x is int32. Internals f16/bf16 MFMA.
//
// R18 = R13 (best verified: 257.2us, k_rec 155us) with hb0 moved global->LDS:
//   hb0L[17][16][HP]: slot 0 = zeros (initial h0), slot t+1 = h0[t].
//   Phase 1 A-frags read hb0L[t]; gate math writes hb0L[t+1] (LDS only --
//   removes the per-step global-store vmcnt drain on the serial chain).
//   Phase 2 A0 reads hb0L[t+1] directly (prefetch regs dropped).
// To fit LDS, head B-frags come from embF global (frag-major, L2-hot,
// R16-verified indexing) instead of embL LDS. LDS: 30976(gLs)+73984(hb0L)
// +4352(hLh)+4352(hnL)+1024(xL) = 114688 B.
// Also fixes R13's latent xL race (R14/R15 crash class): explicit
// __syncthreads() between LDS staging and load_src(0).
// hb0L write/read pattern verified in R17 (passed); embF head verified in
// R16 (passed). Math bitwise identical to R13 -> absmax 0.00390625.
// Tripwires: FETCH >> 50MB = spill; k_rec > 160us = head-load latency.

#define VSZ 433
#define DIM 120
#define BSZ 4096
#define SEQ 16
#define H4  480
#define KP  128
#define NPAD 448
#define NT_HEAD 28
#define TB  16
#define GP  484          // gates LDS row pad (484%32=4 -> 2-way banks = free)
#define HP  136          // h-state LDS row pad in f16/bf16

typedef unsigned int   u32;
typedef unsigned short u16;
typedef __attribute__((ext_vector_type(8))) short    v8bf;
typedef __attribute__((ext_vector_type(8))) _Float16 v8h;
typedef __attribute__((ext_vector_type(4))) float    v4f;

__device__ __forceinline__ u16 f2bf(float f){ // RNE
  union{float f;u32 u;}z; z.f=f;
  u32 u = z.u + 0x7fffu + ((z.u>>16)&1u);
  return (u16)(u>>16);
}
__device__ __forceinline__ u32 packh2(float a, float b){
  union{_Float16 h[2]; u32 u;} z;
  z.h[0] = (_Float16)a; z.h[1] = (_Float16)b;
  return z.u;
}

// ---------------- workspace layout (bytes, 256-aligned) ----------------
#define EW_OFF    0u          // 433*480*4 = 831360
#define B1S_OFF   831488u     // 480*4     = 1920
#define EMBF_OFF  833408u     // 448*128*2 = 114688 (frag-major bf16)

#define PREP_N    (NPAD*KP + H4)             // 57824
#define PREP_BLKS ((PREP_N + 511)/512)       // 113

// ---------------- k_init: EW precompute + embF frag-major + b1s ----------------
__global__ __launch_bounds__(512) void k_init(const float* __restrict__ embed,
                                              const float* __restrict__ Wih0,
                                              const float* __restrict__ bih0,
                                              const float* __restrict__ bhh0,
                                              const float* __restrict__ bih1,
                                              const float* __restrict__ bhh1,
                                              float* __restrict__ EW,
                                              u16* __restrict__ embF,
                                              float* __restrict__ b1s)
{
  __shared__ float e[DIM];
  const int tid = threadIdx.x;
  if (blockIdx.x < VSZ) {
    const int v = blockIdx.x;
    if (tid < DIM) e[tid] = embed[v*DIM + tid];
    __syncthreads();
    if (tid < H4) {
      float acc = bih0[tid] + bhh0[tid];
      #pragma unroll
      for (int k0 = 0; k0 < DIM; k0 += 4) {
        float4 w = *(const float4*)(Wih0 + tid*DIM + k0);
        acc = fmaf(e[k0+0], w.x, acc);
        acc = fmaf(e[k0+1], w.y, acc);
        acc = fmaf(e[k0+2], w.z, acc);
        acc = fmaf(e[k0+3], w.w, acc);
      }
      EW[v*H4 + tid] = acc;
    }
  } else {
    const int idx = (blockIdx.x - VSZ)*512 + tid;
    if (idx < NPAD*KP) {
      // embF frag-major: ((nt*4+kt)*64 + lane)*8 + j = bf16(embed[nt*16+cl][kt*32+quad*8+j])
      int n = idx >> 7, k = idx & 127;
      int nt = n >> 4, cl = n & 15, kt = k >> 5, quad = (k >> 3) & 3, j = k & 7;
      int fidx = ((((nt*4 + kt)*4 + quad)*16 + cl) << 3) + j;
      embF[fidx] = (n < VSZ && k < DIM) ? f2bf(embed[n*DIM + k]) : (u16)0;
    } else if (idx < PREP_N) {
      int g = idx - NPAD*KP;
      b1s[g] = bih1[g] + bhh1[g];
    }
  }
}

// ---------------- k_rec: fused layer0 chain -> layer1 chain + LN + head ----------------
__global__ __launch_bounds__(512) void k_rec(const float* __restrict__ Whh0,
                                             const float* __restrict__ EW,
                                             const int* __restrict__ x,
                                             const float* __restrict__ Wih1,
                                             const float* __restrict__ Whh1,
                                             const float* __restrict__ b1s,
                                             const float* __restrict__ gamma,
                                             const float* __restrict__ beta,
                                             const u16* __restrict__ embF,
                                             float* __restrict__ out)
{
  __shared__ float gLs[TB][GP];                        //  30976 B (both phases)
  __shared__ __align__(16) _Float16 hb0L[SEQ+1][TB][HP];// 73984 B h0: slot t+1 = h0[t]
  __shared__ __align__(16) _Float16 hLh[TB][HP];       //   4352 B h1 state (phase 2)
  __shared__ __align__(16) u16 hnL[TB][HP];            //   4352 B LN'd h1 (bf16)
  __shared__ int xL[TB*SEQ];                           //   1024 B
  // total 114688 B

  const int tid  = threadIdx.x;
  const int wave = tid >> 6, lane = tid & 63;
  const int cl   = lane & 15, quad = lane >> 4;
  const int b0   = blockIdx.x * TB;

  // ---- prologue staging: xL, hb0L zero (incl. pad cols + slot 0), hLh zero
  for (int i = tid; i < TB*SEQ; i += 512) xL[i] = x[b0*SEQ + i];
  {
    u32* p = (u32*)&hb0L[0][0][0];
    for (int i = tid; i < (SEQ+1)*TB*HP/2; i += 512) p[i] = 0u;
    for (int i = tid; i < TB*HP; i += 512) (&hLh[0][0])[i] = (_Float16)0.f;
  }
  __syncthreads();   // staging visible BEFORE load_src(0) — R14/R15 race-class fix

  // phase-B mapping (both phases): wave owns rows {2w,2w+1}; lane l<60 owns {2l,2l+1}
  const int prow = wave*2;
  const bool act = lane < 60;
  const int d0   = lane*2;

  // ================= PHASE 1: layer 0 (R13-verified loop, LDS h0) =================
  {
    v8h Bf[4][4];
    #pragma unroll
    for (int i = 0; i < 4; ++i) {
      const int nt = wave*4 + i;
      const bool vld = (nt < 30);
      const int n = vld ? nt*16 + cl : 0;
      #pragma unroll
      for (int kt = 0; kt < 4; ++kt) {
        const int k0 = kt*32 + quad*8;
        v8h f = {0,0,0,0,0,0,0,0};
        if (vld && k0 < DIM) {
          float4 q0 = *(const float4*)(Whh0 + n*DIM + k0);
          float4 q1 = *(const float4*)(Whh0 + n*DIM + k0 + 4);
          f[0]=(_Float16)q0.x; f[1]=(_Float16)q0.y; f[2]=(_Float16)q0.z; f[3]=(_Float16)q0.w;
          f[4]=(_Float16)q1.x; f[5]=(_Float16)q1.y; f[6]=(_Float16)q1.z; f[7]=(_Float16)q1.w;
        }
        Bf[i][kt] = f;
      }
    }

    float srcv[4][4] = {{0.f,0.f,0.f,0.f},{0.f,0.f,0.f,0.f},
                        {0.f,0.f,0.f,0.f},{0.f,0.f,0.f,0.f}};
    auto load_src = [&](int t) {
      #pragma unroll
      for (int i = 0; i < 4; ++i) {
        const int nt = wave*4 + i;
        if (nt < 30) {
          const int n = nt*16 + cl;
          #pragma unroll
          for (int r = 0; r < 4; ++r)
            srcv[i][r] = EW[(size_t)xL[(quad*4 + r)*SEQ + t]*H4 + n];
        }
      }
    };
    load_src(0);

    float C0[2][2] = {{0.f,0.f},{0.f,0.f}};

    for (int t = 0; t < SEQ; ++t) {
      __syncthreads();   // hb0L[t] (prev phase B / prologue zeros) visible
      v8h Af[4];
      #pragma unroll
      for (int kt = 0; kt < 4; ++kt)
        Af[kt] = *(const v8h*)&hb0L[t][cl][kt*32 + quad*8];
      v4f acc[4];
      #pragma unroll
      for (int i = 0; i < 4; ++i) {
        acc[i][0]=srcv[i][0]; acc[i][1]=srcv[i][1];
        acc[i][2]=srcv[i][2]; acc[i][3]=srcv[i][3];
      }
      #pragma unroll
      for (int i = 0; i < 4; ++i)
        if (wave*4 + i < 30) {
          #pragma unroll
          for (int kt = 0; kt < 4; ++kt)
            acc[i] = __builtin_amdgcn_mfma_f32_16x16x32_f16(Af[kt], Bf[i][kt], acc[i], 0, 0, 0);
        }
      if (t + 1 < SEQ) load_src(t + 1);
      #pragma unroll
      for (int i = 0; i < 4; ++i) {
        const int nt = wave*4 + i;
        if (nt < 30) {
          #pragma unroll
          for (int r = 0; r < 4; ++r)
            gLs[quad*4 + r][nt*16 + cl] = acc[i][r];
        }
      }
      __syncthreads();   // gates visible
      #pragma unroll
      for (int rr = 0; rr < 2; ++rr) {
        const int row = prow + rr;
        if (act) {
          const float2 gi = *(const float2*)&gLs[row][d0      ];
          const float2 gf = *(const float2*)&gLs[row][d0 + 120];
          const float2 gg = *(const float2*)&gLs[row][d0 + 240];
          const float2 go = *(const float2*)&gLs[row][d0 + 360];
          float h2[2];
          #pragma unroll
          for (int k = 0; k < 2; ++k) {
            const float vi = k ? gi.y : gi.x, vf = k ? gf.y : gf.x;
            const float vg = k ? gg.y : gg.x, vo = k ? go.y : go.x;
            const float si = 1.f / (1.f + __expf(-vi));
            const float sf = 1.f / (1.f + __expf(-vf));
            const float tg = 1.f - 2.f / (__expf(2.f*vg) + 1.f);
            const float so = 1.f / (1.f + __expf(-vo));
            const float c  = sf * C0[rr][k] + si * tg;
            C0[rr][k] = c;
            const float tc = 1.f - 2.f / (__expf(2.f*c) + 1.f);
            h2[k] = so * tc;
          }
          *(u32*)&hb0L[t+1][row][d0] = packh2(h2[0], h2[1]);
          // pad cols 120..127 stay zero from prologue
        }
      }
    }
  }

  __syncthreads();   // phase 1 complete: hb0L fully populated

  // anti-hoist guard: keep phase-2 weight loads below phase 1 (R9 spill trap)
  const float* Wih1p = Wih1;
  const float* Whh1p = Whh1;
  const float* b1sp  = b1s;
  asm volatile("" : "+s"(Wih1p), "+s"(Whh1p), "+s"(b1sp) :: "memory");

  // ================= PHASE 2: layer 1 + LN + head (R13-verified loop) =================
  v8h Bi[4][4], Bh[4][4];
  float bias[4];
  #pragma unroll
  for (int i = 0; i < 4; ++i) {
    const int nt = wave*4 + i;
    const bool vld = (nt < 30);
    const int n = vld ? nt*16 + cl : 0;
    bias[i] = vld ? b1sp[n] : 0.f;
    #pragma unroll
    for (int kt = 0; kt < 4; ++kt) {
      const int k0 = kt*32 + quad*8;
      v8h fi = {0,0,0,0,0,0,0,0}, fh = {0,0,0,0,0,0,0,0};
      if (vld && k0 < DIM) {
        float4 q0 = *(const float4*)(Wih1p + n*DIM + k0);
        float4 q1 = *(const float4*)(Wih1p + n*DIM + k0 + 4);
        fi[0]=(_Float16)q0.x; fi[1]=(_Float16)q0.y; fi[2]=(_Float16)q0.z; fi[3]=(_Float16)q0.w;
        fi[4]=(_Float16)q1.x; fi[5]=(_Float16)q1.y; fi[6]=(_Float16)q1.z; fi[7]=(_Float16)q1.w;
        float4 p0 = *(const float4*)(Whh1p + n*DIM + k0);
        float4 p1 = *(const float4*)(Whh1p + n*DIM + k0 + 4);
        fh[0]=(_Float16)p0.x; fh[1]=(_Float16)p0.y; fh[2]=(_Float16)p0.z; fh[3]=(_Float16)p0.w;
        fh[4]=(_Float16)p1.x; fh[5]=(_Float16)p1.y; fh[6]=(_Float16)p1.z; fh[7]=(_Float16)p1.w;
      }
      Bi[i][kt] = fi;
      Bh[i][kt] = fh;
    }
  }

  float gmm[2] = {0.f, 0.f}, bta[2] = {0.f, 0.f};
  if (act) {
    gmm[0] = gamma[d0]; gmm[1] = gamma[d0+1];
    bta[0] = beta[d0];  bta[1] = beta[d0+1];
  }
  float C1[2][2] = {{0.f,0.f},{0.f,0.f}};
  __syncthreads();

  for (int t = 0; t < SEQ; ++t) {
    v8h A0c[4], A1[4];
    #pragma unroll
    for (int kt = 0; kt < 4; ++kt) {
      A0c[kt] = *(const v8h*)&hb0L[t+1][cl][kt*32 + quad*8];   // h0[t] from LDS
      A1[kt]  = *(const v8h*)&hLh[cl][kt*32 + quad*8];
    }
    v4f acc[4];
    #pragma unroll
    for (int i = 0; i < 4; ++i)
      acc[i] = (v4f){bias[i], bias[i], bias[i], bias[i]};
    #pragma unroll
    for (int i = 0; i < 4; ++i)
      if (wave*4 + i < 30) {
        #pragma unroll
        for (int kt = 0; kt < 4; ++kt) {
          acc[i] = __builtin_amdgcn_mfma_f32_16x16x32_f16(A0c[kt], Bi[i][kt], acc[i], 0, 0, 0);
          acc[i] = __builtin_amdgcn_mfma_f32_16x16x32_f16(A1[kt],  Bh[i][kt], acc[i], 0, 0, 0);
        }
      }
    #pragma unroll
    for (int i = 0; i < 4; ++i) {
      const int nt = wave*4 + i;
      if (nt < 30) {
        #pragma unroll
        for (int r = 0; r < 4; ++r)
          gLs[quad*4 + r][nt*16 + cl] = acc[i][r];
      }
    }
    __syncthreads();   // sync1: gates visible
    float h2[2][2] = {{0.f,0.f},{0.f,0.f}};
    float s1[2] = {0.f, 0.f}, s2[2] = {0.f, 0.f};
    #pragma unroll
    for (int rr = 0; rr < 2; ++rr) {
      const int row = prow + rr;
      if (act) {
        const float2 gi = *(const float2*)&gLs[row][d0      ];
        const float2 gf = *(const float2*)&gLs[row][d0 + 120];
        const float2 gg = *(const float2*)&gLs[row][d0 + 240];
        const float2 go = *(const float2*)&gLs[row][d0 + 360];
        #pragma unroll
        for (int k = 0; k < 2; ++k) {
          const float vi = k ? gi.y : gi.x, vf = k ? gf.y : gf.x;
          const float vg = k ? gg.y : gg.x, vo = k ? go.y : go.x;
          const float si = 1.f / (1.f + __expf(-vi));
          const float sf = 1.f / (1.f + __expf(-vf));
          const float tg = 1.f - 2.f / (__expf(2.f*vg) + 1.f);
          const float so = 1.f / (1.f + __expf(-vo));
          const float c  = sf * C1[rr][k] + si * tg;
          C1[rr][k] = c;
          const float tc = 1.f - 2.f / (__expf(2.f*c) + 1.f);
          const float h  = so * tc;
          h2[rr][k] = h;
          s1[rr] += h;
          s2[rr] = fmaf(h, h, s2[rr]);
        }
        *(u32*)&hLh[row][d0] = packh2(h2[rr][0], h2[rr][1]);
      }
    }
    // LN reduction across the wave (idle lanes contribute 0)
    #pragma unroll
    for (int m = 32; m >= 1; m >>= 1) {
      s1[0] += __shfl_xor(s1[0], m);
      s2[0] += __shfl_xor(s2[0], m);
      s1[1] += __shfl_xor(s1[1], m);
      s2[1] += __shfl_xor(s2[1], m);
    }
    #pragma unroll
    for (int rr = 0; rr < 2; ++rr) {
      const int row = prow + rr;
      const float mu = s1[rr] * (1.f/DIM);
      const float var = s2[rr] * (1.f/DIM) - mu*mu;
      const float rs = rsqrtf(var + 1e-5f);
      if (act) {
        const float v0 = fmaf((h2[rr][0] - mu)*rs, gmm[0], bta[0]);
        const float v1 = fmaf((h2[rr][1] - mu)*rs, gmm[1], bta[1]);
        *(u32*)&hnL[row][d0] = (u32)f2bf(v0) | ((u32)f2bf(v1) << 16);
      } else {
        *(u32*)&hnL[row][120 + 2*(lane - 60)] = 0u;   // zero pad cols
      }
    }
    __syncthreads();   // sync2: hLh + hnL stable

    // ---- fused tied-embedding head for step t (A from hnL, B from embF/L2)
    {
      v8bf a[4];
      #pragma unroll
      for (int kt = 0; kt < 4; ++kt)
        a[kt] = *(const v8bf*)&hnL[cl][kt*32 + quad*8];
      #pragma unroll
      for (int j = 0; j < 4; ++j) {
        const int nt = wave + 8*j;            // waves 0-3: 4 tiles, 4-7: 3 tiles
        if (nt < NT_HEAD) {
          v8bf bfr[4];
          #pragma unroll
          for (int kt = 0; kt < 4; ++kt)
            bfr[kt] = *(const v8bf*)&embF[(((size_t)nt*4 + kt)*64 + lane)*8];
          v4f hacc = {0.f, 0.f, 0.f, 0.f};
          #pragma unroll
          for (int kt = 0; kt < 4; ++kt)
            hacc = __builtin_amdgcn_mfma_f32_16x16x32_bf16(a[kt], bfr[kt], hacc, 0, 0, 0);
          const int n = nt*16 + cl;
          if (n < VSZ) {
            #pragma unroll
            for (int r = 0; r < 4; ++r)
              out[((size_t)(b0 + quad*4 + r)*SEQ + t)*VSZ + n] = hacc[r];
          }
        }
      }
    }
  }
}

// ---------------- launch ----------------
extern "C" void kernel_launch(void* const* d_in, const int* in_sizes, int n_in,
                              void* d_out, int out_size, void* d_ws, size_t ws_size,
                              hipStream_t stream)
{
  (void)in_sizes; (void)n_in; (void)out_size; (void)ws_size;
  const int*   x     = (const int*)d_in[0];
  const float* embed = (const float*)d_in[1];
  const float* Wih0  = (const float*)d_in[2];
  const float* Whh0  = (const float*)d_in[3];
  const float* bih0  = (const float*)d_in[4];
  const float* bhh0  = (const float*)d_in[5];
  const float* Wih1  = (const float*)d_in[6];
  const float* Whh1  = (const float*)d_in[7];
  const float* bih1  = (const float*)d_in[8];
  const float* bhh1  = (const float*)d_in[9];
  const float* gamma = (const float*)d_in[10];
  const float* beta  = (const float*)d_in[11];

  char* ws = (char*)d_ws;
  float* EW   = (float*)(ws + EW_OFF);
  float* b1s  = (float*)(ws + B1S_OFF);
  u16*   embF = (u16*)(ws + EMBF_OFF);

  k_init<<<VSZ + PREP_BLKS, 512, 0, stream>>>(embed, Wih0, bih0, bhh0, bih1, bhh1,
                                              EW, embF, b1s);
  k_rec <<<BSZ/TB, 512, 0, stream>>>(Whh0, EW, x, Wih1, Whh1, b1s, gamma, beta,
                                     embF, (float*)d_out);
}